// Round 3
// baseline (457.948 us; speedup 1.0000x reference)
//
#include <hip/hip_runtime.h>

#define N_BINS 10
#define EPS 1e-7f

typedef unsigned int uint;

#define TPB 256                      // threads per block
#define PAIRS_PER_CHUNK 256          // pairs staged per block iteration
#define CHUNK_F4 (PAIRS_PER_CHUNK * 5)   // 1280 float4 = 20 KB LDS

// ---------------------------------------------------------------------------
// ws layout (uint): [0..9] counts, [10..19] correct
// ---------------------------------------------------------------------------

__global__ void zero_ws_kernel(uint* ws) {
    if (threadIdx.x < 2 * N_BINS) ws[threadIdx.x] = 0u;
}

__device__ __forceinline__ void process_row(const float* v, int label,
                                            uint& c8, uint& k8, uint& c9, uint& k9,
                                            uint* scount, uint* scorrect) {
    // sm = logits - EPS, per element (faithful to reference)
    float m = v[0] - EPS;
    int am = 0;
#pragma unroll
    for (int j = 1; j < 10; ++j) {
        float s = v[j] - EPS;
        if (s > m) { m = s; am = j; }   // strict > keeps FIRST max (jnp.argmax)
    }
    int acc = (am == label) ? 1 : 0;

    // searchsorted(boundaries, conf, side=left) - 1 == (#boundaries < conf) - 1
    int idx = 0;
#pragma unroll
    for (int j = 0; j <= 10; ++j) {
        idx += ((0.1f * (float)j) < m) ? 1 : 0;
    }
    int bin = idx - 1;

    if (bin == 9)      { c9++; k9 += acc; }          // ~65% of rows
    else if (bin == 8) { c8++; k8 += acc; }          // ~13% of rows
    else if (bin >= 0 && bin < 8) {                  // rare path
        atomicAdd(&scount[bin], 1u);
        if (acc) atomicAdd(&scorrect[bin], 1u);
    }
    // bin < 0 (conf <= 0) or bin >= 10: overflow segment, dropped
}

__global__ void __launch_bounds__(TPB)
hist_kernel(const float* __restrict__ logits, const int* __restrict__ labels,
            uint* __restrict__ ws, int npairs, int n_rows) {
    __shared__ float4 stage[CHUNK_F4];
    __shared__ uint scount[N_BINS];
    __shared__ uint scorrect[N_BINS];
    if (threadIdx.x < N_BINS) { scount[threadIdx.x] = 0u; scorrect[threadIdx.x] = 0u; }
    __syncthreads();

    uint c8 = 0, k8 = 0, c9 = 0, k9 = 0;

    const int tid   = threadIdx.x;
    const int nfull = npairs / PAIRS_PER_CHUNK;
    const float4* gsrc = reinterpret_cast<const float4*>(logits);
    const int2*   lsrc = reinterpret_cast<const int2*>(labels);

    for (int c = blockIdx.x; c < nfull; c += gridDim.x) {
        const size_t base = (size_t)c * CHUNK_F4;

        // coalesced global loads: lane-contiguous float4 (1 KiB / wave / instr)
        float4 r0 = gsrc[base + tid];
        float4 r1 = gsrc[base + tid + 1 * TPB];
        float4 r2 = gsrc[base + tid + 2 * TPB];
        float4 r3 = gsrc[base + tid + 3 * TPB];
        float4 r4 = gsrc[base + tid + 4 * TPB];
        int2 lab = lsrc[(size_t)c * PAIRS_PER_CHUNK + tid];

        // bank-perfect LDS writes (lane-contiguous 16 B)
        stage[tid]           = r0;
        stage[tid + 1 * TPB] = r1;
        stage[tid + 2 * TPB] = r2;
        stage[tid + 3 * TPB] = r3;
        stage[tid + 4 * TPB] = r4;
        __syncthreads();

        // each thread reads its own pair (80 B) from LDS
        float4 a0 = stage[tid * 5 + 0];
        float4 a1 = stage[tid * 5 + 1];
        float4 a2 = stage[tid * 5 + 2];
        float4 a3 = stage[tid * 5 + 3];
        float4 a4 = stage[tid * 5 + 4];
        float v[20] = { a0.x, a0.y, a0.z, a0.w, a1.x, a1.y, a1.z, a1.w,
                        a2.x, a2.y, a2.z, a2.w, a3.x, a3.y, a3.z, a3.w,
                        a4.x, a4.y, a4.z, a4.w };

        process_row(v,      lab.x, c8, k8, c9, k9, scount, scorrect);
        process_row(v + 10, lab.y, c8, k8, c9, k9, scount, scorrect);
        __syncthreads();   // protect stage before next-iteration overwrite
    }

    // leftover pairs (npairs % 256) + odd tail row — not hit for the 8M bench
    const int done_pairs = nfull * PAIRS_PER_CHUNK;
    const int leftover   = npairs - done_pairs;
    if (blockIdx.x == 0) {
        if (tid < leftover) {
            const float* rp = logits + (size_t)(done_pairs + tid) * 10;
            float v[20];
#pragma unroll
            for (int j = 0; j < 20; ++j) v[j] = rp[j];
            int2 lab = lsrc[done_pairs + tid];
            process_row(v,      lab.x, c8, k8, c9, k9, scount, scorrect);
            process_row(v + 10, lab.y, c8, k8, c9, k9, scount, scorrect);
        }
        if (tid == 0 && (n_rows & 1)) {
            const float* rp = logits + (size_t)(n_rows - 1) * 10;
            float t[10];
#pragma unroll
            for (int j = 0; j < 10; ++j) t[j] = rp[j];
            process_row(t, labels[n_rows - 1], c8, k8, c9, k9, scount, scorrect);
        }
    }

    // wave-level reduction of the hot-bin register accumulators
#pragma unroll
    for (int off = 32; off > 0; off >>= 1) {
        c8 += __shfl_down(c8, off);
        k8 += __shfl_down(k8, off);
        c9 += __shfl_down(c9, off);
        k9 += __shfl_down(k9, off);
    }
    if ((threadIdx.x & 63) == 0) {
        atomicAdd(&scount[8], c8);
        atomicAdd(&scorrect[8], k8);
        atomicAdd(&scount[9], c9);
        atomicAdd(&scorrect[9], k9);
    }
    __syncthreads();

    if (threadIdx.x < N_BINS) {
        atomicAdd(&ws[threadIdx.x], scount[threadIdx.x]);
        atomicAdd(&ws[N_BINS + threadIdx.x], scorrect[threadIdx.x]);
    }
}

__global__ void finalize_kernel(const uint* __restrict__ ws, float* __restrict__ out) {
    if (threadIdx.x < N_BINS) {
        uint c = ws[threadIdx.x];
        uint k = ws[N_BINS + threadIdx.x];
        out[threadIdx.x] = (c > 0u) ? ((float)k / (float)c) : 0.0f;
    }
}

extern "C" void kernel_launch(void* const* d_in, const int* in_sizes, int n_in,
                              void* d_out, int out_size, void* d_ws, size_t ws_size,
                              hipStream_t stream) {
    const float* logits = (const float*)d_in[0];
    const int*   labels = (const int*)d_in[1];
    float*       out    = (float*)d_out;
    uint*        ws     = (uint*)d_ws;

    const int n_rows = in_sizes[1];          // N = 8,000,000
    const int npairs = n_rows / 2;

    zero_ws_kernel<<<1, 64, 0, stream>>>(ws);

    // 2048 blocks x 256 threads: 8 blocks/CU (20 KB LDS each) = 32 waves/CU,
    // exactly resident; 16384 chunks / 2048 blocks = 8 chunks per block.
    int blocks = 2048;
    int nchunks = npairs / PAIRS_PER_CHUNK;
    if (nchunks < 1) nchunks = 1;
    if (blocks > nchunks) blocks = nchunks;
    hist_kernel<<<blocks, TPB, 0, stream>>>(logits, labels, ws, npairs, n_rows);

    finalize_kernel<<<1, 64, 0, stream>>>(ws, out);
}

// Round 5
// 451.564 us; speedup vs baseline: 1.0141x; 1.0141x over previous
//
#include <hip/hip_runtime.h>

#define N_BINS 10
#define EPS 1e-7f

typedef unsigned int uint;

#define TPB 256                      // threads per block
#define PAIRS_PER_CHUNK 256          // pairs staged per block iteration
#define CHUNK_F4 (PAIRS_PER_CHUNK * 5)   // 1280 float4 = 20 KB LDS

// ---------------------------------------------------------------------------
// ws layout (uint, column-major partials): partials[j*nblocks + b]
//   j in [0,10)  : per-block bin counts
//   j in [10,20) : per-block bin correct-counts
// Every block writes all 20 of its slots unconditionally -> no zeroing needed
// (ws is poisoned 0xAA before every launch).
// ---------------------------------------------------------------------------

__device__ __forceinline__ void process_row(const float* v, int label,
                                            uint& c8, uint& k8, uint& c9, uint& k9,
                                            uint* scount, uint* scorrect) {
    // sm = logits - EPS, per element (faithful to reference)
    float m = v[0] - EPS;
    int am = 0;
#pragma unroll
    for (int j = 1; j < 10; ++j) {
        float s = v[j] - EPS;
        if (s > m) { m = s; am = j; }   // strict > keeps FIRST max (jnp.argmax)
    }
    int acc = (am == label) ? 1 : 0;

    // searchsorted(boundaries, conf, side=left) - 1 == (#boundaries < conf) - 1
    int idx = 0;
#pragma unroll
    for (int j = 0; j <= 10; ++j) {
        idx += ((0.1f * (float)j) < m) ? 1 : 0;
    }
    int bin = idx - 1;

    if (bin == 9)      { c9++; k9 += acc; }          // ~65% of rows
    else if (bin == 8) { c8++; k8 += acc; }          // ~13% of rows
    else if (bin >= 0 && bin < 8) {                  // rare path, LDS atomics
        atomicAdd(&scount[bin], 1u);
        if (acc) atomicAdd(&scorrect[bin], 1u);
    }
    // bin < 0 (conf <= 0) or bin >= 10: overflow segment, dropped
}

__global__ void __launch_bounds__(TPB)
hist_kernel(const float* __restrict__ logits, const int* __restrict__ labels,
            uint* __restrict__ partials, int npairs, int n_rows, int nblocks) {
    __shared__ float4 stage[CHUNK_F4];
    __shared__ uint scount[N_BINS];
    __shared__ uint scorrect[N_BINS];
    if (threadIdx.x < N_BINS) { scount[threadIdx.x] = 0u; scorrect[threadIdx.x] = 0u; }
    __syncthreads();

    uint c8 = 0, k8 = 0, c9 = 0, k9 = 0;

    const int tid   = threadIdx.x;
    const int nfull = npairs / PAIRS_PER_CHUNK;
    const float4* gsrc = reinterpret_cast<const float4*>(logits);
    const int2*   lsrc = reinterpret_cast<const int2*>(labels);

    for (int c = blockIdx.x; c < nfull; c += gridDim.x) {
        const size_t base = (size_t)c * CHUNK_F4;

        // coalesced global loads: lane-contiguous float4 (1 KiB / wave / instr)
        float4 r0 = gsrc[base + tid];
        float4 r1 = gsrc[base + tid + 1 * TPB];
        float4 r2 = gsrc[base + tid + 2 * TPB];
        float4 r3 = gsrc[base + tid + 3 * TPB];
        float4 r4 = gsrc[base + tid + 4 * TPB];
        int2 lab = lsrc[(size_t)c * PAIRS_PER_CHUNK + tid];

        // bank-perfect LDS writes (lane-contiguous 16 B)
        stage[tid]           = r0;
        stage[tid + 1 * TPB] = r1;
        stage[tid + 2 * TPB] = r2;
        stage[tid + 3 * TPB] = r3;
        stage[tid + 4 * TPB] = r4;
        __syncthreads();

        // each thread reads its own pair (80 B) from LDS
        float4 a0 = stage[tid * 5 + 0];
        float4 a1 = stage[tid * 5 + 1];
        float4 a2 = stage[tid * 5 + 2];
        float4 a3 = stage[tid * 5 + 3];
        float4 a4 = stage[tid * 5 + 4];
        float v[20] = { a0.x, a0.y, a0.z, a0.w, a1.x, a1.y, a1.z, a1.w,
                        a2.x, a2.y, a2.z, a2.w, a3.x, a3.y, a3.z, a3.w,
                        a4.x, a4.y, a4.z, a4.w };

        process_row(v,      lab.x, c8, k8, c9, k9, scount, scorrect);
        process_row(v + 10, lab.y, c8, k8, c9, k9, scount, scorrect);
        __syncthreads();   // protect stage before next-iteration overwrite
    }

    // leftover pairs (npairs % 256) + odd tail row — not hit for the 8M bench
    const int done_pairs = nfull * PAIRS_PER_CHUNK;
    const int leftover   = npairs - done_pairs;
    if (blockIdx.x == 0) {
        if (tid < leftover) {
            const float* rp = logits + (size_t)(done_pairs + tid) * 10;
            float v[20];
#pragma unroll
            for (int j = 0; j < 20; ++j) v[j] = rp[j];
            int2 lab = lsrc[done_pairs + tid];
            process_row(v,      lab.x, c8, k8, c9, k9, scount, scorrect);
            process_row(v + 10, lab.y, c8, k8, c9, k9, scount, scorrect);
        }
        if (tid == 0 && (n_rows & 1)) {
            const float* rp = logits + (size_t)(n_rows - 1) * 10;
            float t[10];
#pragma unroll
            for (int j = 0; j < 10; ++j) t[j] = rp[j];
            process_row(t, labels[n_rows - 1], c8, k8, c9, k9, scount, scorrect);
        }
    }

    // wave-level reduction of the hot-bin register accumulators
#pragma unroll
    for (int off = 32; off > 0; off >>= 1) {
        c8 += __shfl_down(c8, off);
        k8 += __shfl_down(k8, off);
        c9 += __shfl_down(c9, off);
        k9 += __shfl_down(k9, off);
    }
    if ((threadIdx.x & 63) == 0) {
        atomicAdd(&scount[8], c8);
        atomicAdd(&scorrect[8], k8);
        atomicAdd(&scount[9], c9);
        atomicAdd(&scorrect[9], k9);
    }
    __syncthreads();

    // plain per-block partial stores — NO global atomics (kills the serialized
    // same-cache-line atomic tail: 41k atomics on one 80-B line ~ 50 us)
    if (threadIdx.x < N_BINS) {
        partials[(size_t)threadIdx.x * nblocks + blockIdx.x]            = scount[threadIdx.x];
        partials[(size_t)(N_BINS + threadIdx.x) * nblocks + blockIdx.x] = scorrect[threadIdx.x];
    }
}

__global__ void __launch_bounds__(256)
finalize_kernel(const uint* __restrict__ partials, float* __restrict__ out, int nblocks) {
    __shared__ uint red[2 * N_BINS];
    const int tid = threadIdx.x;
    if (tid < 2 * N_BINS) red[tid] = 0u;
    __syncthreads();

    uint s[2 * N_BINS];
#pragma unroll
    for (int j = 0; j < 2 * N_BINS; ++j) s[j] = 0u;

    for (int p = tid; p < nblocks; p += blockDim.x) {
#pragma unroll
        for (int j = 0; j < 2 * N_BINS; ++j)
            s[j] += partials[(size_t)j * nblocks + p];   // coalesced per row
    }

#pragma unroll
    for (int j = 0; j < 2 * N_BINS; ++j) {
#pragma unroll
        for (int off = 32; off > 0; off >>= 1)
            s[j] += __shfl_down(s[j], off);
    }
    if ((tid & 63) == 0) {
#pragma unroll
        for (int j = 0; j < 2 * N_BINS; ++j)
            atomicAdd(&red[j], s[j]);
    }
    __syncthreads();

    if (tid < N_BINS) {
        uint c = red[tid];
        uint k = red[N_BINS + tid];
        out[tid] = (c > 0u) ? ((float)k / (float)c) : 0.0f;
    }
}

extern "C" void kernel_launch(void* const* d_in, const int* in_sizes, int n_in,
                              void* d_out, int out_size, void* d_ws, size_t ws_size,
                              hipStream_t stream) {
    const float* logits = (const float*)d_in[0];
    const int*   labels = (const int*)d_in[1];
    float*       out    = (float*)d_out;
    uint*        ws     = (uint*)d_ws;

    const int n_rows = in_sizes[1];          // N = 8,000,000
    const int npairs = n_rows / 2;

    // 2048 blocks x 256 threads: 8 blocks/CU (20 KB LDS each) = 32 waves/CU.
    int blocks = 2048;
    int nchunks = npairs / PAIRS_PER_CHUNK;
    if (nchunks < 1) nchunks = 1;
    if (blocks > nchunks) blocks = nchunks;

    hist_kernel<<<blocks, TPB, 0, stream>>>(logits, labels, ws, npairs, n_rows, blocks);
    finalize_kernel<<<1, 256, 0, stream>>>(ws, out, blocks);
}